// Round 2
// baseline (1457.619 us; speedup 1.0000x reference)
//
#include <hip/hip_runtime.h>

// Balanced sinkhorn, persistent-kernel version: one 256-block x 256-thread
// kernel does all 10 outer iterations. Each block owns 64 rows; E~ and feat
// tiles live in LDS (133 KB -> 1 block/CU -> all 256 blocks co-resident ->
// software grid barrier is safe). Global K-space reductions use padded f64
// atomics; w/buf/k2 replicated per block (deterministic f64).

namespace {

constexpr int BATCH = 16384;
constexpr int KDIM  = 256;
constexpr int NBLK  = 256;   // == CU count; required for barrier safety
constexpr int ROWS  = 64;    // rows per block
constexpr int PAD   = 16;    // doubles per accumulator slot (128 B line)
constexpr int SLOT  = KDIM * PAD;  // 4096 doubles per accumulator array
constexpr float L2E20 = 28.853900817779268f;  // 20 * log2(e)

__device__ __forceinline__ double fast_exp_d(double x) {
  const double LOG2E  = 1.4426950408889634074;
  const double LN2_HI = 6.93147180369123816490e-01;
  const double LN2_LO = 1.90821492927058770002e-10;
  double n = rint(x * LOG2E);
  double t = fma(-n, LN2_HI, x);
  t = fma(-n, LN2_LO, t);
  double p = 2.4801587301587302e-05;
  p = fma(p, t, 1.9841269841269841e-04);
  p = fma(p, t, 1.3888888888888889e-03);
  p = fma(p, t, 8.3333333333333333e-03);
  p = fma(p, t, 4.1666666666666664e-02);
  p = fma(p, t, 1.6666666666666666e-01);
  p = fma(p, t, 0.5);
  p = fma(p, t, 1.0);
  p = fma(p, t, 1.0);
  long long ni = (long long)n;
  double s = __longlong_as_double((unsigned long long)(ni + 1023LL) << 52);
  return p * s;
}

__device__ __forceinline__ double wave_sum_d(double v) {
#pragma unroll
  for (int o = 32; o > 0; o >>= 1) v += __shfl_down(v, o);
  return v;
}

__device__ __forceinline__ double wave_max_d(double v) {
#pragma unroll
  for (int o = 32; o > 0; o >>= 1) v = fmax(v, __shfl_down(v, o));
  return v;
}

__device__ __forceinline__ double aload(const double* p) {
  return __hip_atomic_load(p, __ATOMIC_RELAXED, __HIP_MEMORY_SCOPE_AGENT);
}
__device__ __forceinline__ void azero(double* p) {
  __hip_atomic_store(p, 0.0, __ATOMIC_RELAXED, __HIP_MEMORY_SCOPE_AGENT);
}

// Sense-reversing grid barrier; all NBLK blocks are co-resident (1/CU).
__device__ __forceinline__ void grid_barrier(unsigned* bar) {
  __syncthreads();
  if (threadIdx.x == 0) {
    __threadfence();
    unsigned* cnt = bar;
    unsigned* gen = bar + 32;  // separate cacheline
    unsigned g = __hip_atomic_load(gen, __ATOMIC_RELAXED, __HIP_MEMORY_SCOPE_AGENT);
    if (__hip_atomic_fetch_add(cnt, 1u, __ATOMIC_ACQ_REL,
                               __HIP_MEMORY_SCOPE_AGENT) == (unsigned)NBLK - 1) {
      __hip_atomic_store(cnt, 0u, __ATOMIC_RELAXED, __HIP_MEMORY_SCOPE_AGENT);
      __hip_atomic_fetch_add(gen, 1u, __ATOMIC_RELEASE, __HIP_MEMORY_SCOPE_AGENT);
    } else {
      while (__hip_atomic_load(gen, __ATOMIC_ACQUIRE,
                               __HIP_MEMORY_SCOPE_AGENT) == g) {
        __builtin_amdgcn_s_sleep(2);
      }
    }
    __threadfence();
  }
  __syncthreads();
}

}  // namespace

// ---------------------------------------------------------------------------
// Zero u0 + parity-0 accumulator set + barrier state (ws is 0xAA-poisoned).
__global__ __launch_bounds__(256) void kInitWS(double* __restrict__ ws) {
  size_t n = (size_t)7 * SLOT;  // u0g + 6 arrays of set 0, contiguous
  size_t stride = (size_t)gridDim.x * blockDim.x;
  for (size_t j = (size_t)blockIdx.x * blockDim.x + threadIdx.x; j < n; j += stride)
    ws[j] = 0.0;
  if (blockIdx.x == 0 && threadIdx.x == 0) {
    unsigned* bar = (unsigned*)(ws + (size_t)13 * SLOT);
    bar[0] = 0u;   // cnt
    bar[32] = 0u;  // gen
  }
}

// ---------------------------------------------------------------------------
__global__ __launch_bounds__(256, 1) void sink_main(
    const float* __restrict__ feat, const float* __restrict__ w_in,
    float* __restrict__ out, double* __restrict__ ws) {
  __shared__ float  Et[ROWS * KDIM];   // 64 KB  E~ tile
  __shared__ float  Ft[ROWS * KDIM];   // 64 KB  feat tile
  __shared__ double alpha[KDIM];       // per-phase k-weights
  __shared__ double v1s[ROWS], v2s[ROWS], v3s[ROWS];
  __shared__ double grow[ROWS];        // per-row scratch (gv3 / raw sums)
  __shared__ double wrow[ROWS];        // per-row weights for column passes
  __shared__ double sbr[ROWS];         // exp(20*M[b]) f64
  __shared__ float  mrow[ROWS];
  __shared__ double sred[8];

  const int t = threadIdx.x, bid = blockIdx.x;
  const int wv = t >> 6, lane = t & 63;
  const int b0 = bid * ROWS;

  double* u0g = ws;
  auto acc = [&](int p, int a) -> double* {
    return ws + (size_t)(1 + p * 6 + a) * SLOT;
  };
  unsigned* bar = (unsigned*)(ws + (size_t)13 * SLOT);

  // ---- block reductions (256-wide) via wave shuffles + LDS
  auto blk_sum = [&](double v) -> double {
    v = wave_sum_d(v);
    __syncthreads();
    if (lane == 0) sred[wv] = v;
    __syncthreads();
    return sred[0] + sred[1] + sred[2] + sred[3];
  };
  auto blk_max = [&](double v) -> double {
    v = wave_max_d(v);
    __syncthreads();
    if (lane == 0) sred[wv + 4] = v;
    __syncthreads();
    return fmax(fmax(sred[4], sred[5]), fmax(sred[6], sred[7]));
  };

  // ---- per-row pass: dstv[r] = sum_k alpha[k]*E~[r,k]
  auto row_pass = [&](double* dstv) {
    double a0 = alpha[4 * lane + 0], a1 = alpha[4 * lane + 1];
    double a2 = alpha[4 * lane + 2], a3 = alpha[4 * lane + 3];
#pragma unroll 4
    for (int r = wv; r < ROWS; r += 4) {
      float4 e4 = ((const float4*)(Et + r * KDIM))[lane];
      double s1 = a0 * (double)e4.x + a1 * (double)e4.y +
                  a2 * (double)e4.z + a3 * (double)e4.w;
      s1 = wave_sum_d(s1);
      if (lane == 0) dstv[r] = s1;
    }
  };

  // ---- per-k pass: atomic dst[k] += sum_r E~[r,k]*wrow[r]
  auto col_accum = [&](double* dst) {
    double a = 0.0;
#pragma unroll 8
    for (int r = 0; r < ROWS; ++r) a += (double)Et[r * KDIM + t] * wrow[r];
    unsafeAtomicAdd(&dst[t * PAD], a);
  };

  // ================= setup =================
  {  // stage feat tile (coalesced float4)
    const float4* src = (const float4*)(feat + (size_t)b0 * KDIM);
    float4* dst = (float4*)Ft;
#pragma unroll
    for (int s = 0; s < 16; ++s) dst[s * 256 + t] = src[s * 256 + t];
  }
  __syncthreads();
  // row max + f64 row scale
  for (int r = wv; r < ROWS; r += 4) {
    float4 f4 = ((const float4*)(Ft + r * KDIM))[lane];
    float m = fmaxf(fmaxf(f4.x, f4.y), fmaxf(f4.z, f4.w));
#pragma unroll
    for (int o = 32; o > 0; o >>= 1) m = fmaxf(m, __shfl_down(m, o));
    if (lane == 0) {
      mrow[r] = m;
      sbr[r] = fast_exp_d(20.0 * (double)m);
    }
  }
  __syncthreads();
  // E~ tile + u0 partial accumulation
  {
    double a0 = 0.0;
#pragma unroll 8
    for (int r = 0; r < ROWS; ++r) {
      float e = exp2f((Ft[r * KDIM + t] - mrow[r]) * L2E20);
      Et[r * KDIM + t] = e;
      a0 += (double)e * sbr[r];
    }
    unsafeAtomicAdd(&u0g[t * PAD], a0);
  }
  // replicated optimizer state + k2 = softmax(w)
  float w_t = w_in[t], buf_t = 0.0f;
  double k2_t;
  {
    double x = (double)w_t;
    double m = blk_max(x);
    double e = fast_exp_d(x - m);
    double s = blk_sum(e);
    k2_t = e / s;
  }
  grid_barrier(bar);  // u0 complete
  const double u0_t = aload(&u0g[t * PAD]);

  // ================= outer loop =================
  for (int it = 0; it < 10; ++it) {
    const int p = it & 1;
    double* u1g   = acc(p, 0);
    double* u2g   = acc(p, 1);
    double* gdirg = acc(p, 2);
    double* t3g   = acc(p, 3);
    double* ga2g  = acc(p, 4);
    double* ga1g  = acc(p, 5);

    // ---- Phase A: v1~ ; accumulate u1
    alpha[t] = k2_t / u0_t;
    __syncthreads();
    row_pass(v1s);
    __syncthreads();
    if (t < ROWS) wrow[t] = 1.0 / (16384.0 * v1s[t]);
    __syncthreads();
    col_accum(u1g);
    grid_barrier(bar);

    // ---- Phase B: v2~ ; accumulate u2 ; zero other parity set
    alpha[t] = k2_t / aload(&u1g[t * PAD]);
    __syncthreads();
    row_pass(v2s);
    __syncthreads();
    if (t < ROWS) wrow[t] = 1.0 / (16384.0 * v2s[t]);
    if (it < 9 && bid < 6) azero(&acc(1 - p, bid)[t * PAD]);
    __syncthreads();
    col_accum(u2g);
    grid_barrier(bar);

    if (it == 9) {
      // ---- output: Q[b,k] = alpha3[k]*E~[r,k]/v3~[b]
      alpha[t] = k2_t / aload(&u2g[t * PAD]);
      __syncthreads();
      row_pass(v3s);
      __syncthreads();
      if (t < ROWS) wrow[t] = 1.0 / v3s[t];
      __syncthreads();
      double a3 = alpha[t];
#pragma unroll 4
      for (int r = 0; r < ROWS; ++r)
        out[(size_t)(b0 + r) * KDIM + t] =
            (float)(a3 * (double)Et[r * KDIM + t] * wrow[r]);
      return;
    }

    // ---- Phase C: v3~, gv3~; accumulate gdir, t3
    alpha[t] = k2_t / aload(&u2g[t * PAD]);
    __syncthreads();
    {
      double a0 = alpha[4 * lane + 0], a1 = alpha[4 * lane + 1];
      double a2 = alpha[4 * lane + 2], a3 = alpha[4 * lane + 3];
#pragma unroll 2
      for (int r = wv; r < ROWS; r += 4) {
        float4 e4 = ((const float4*)(Et + r * KDIM))[lane];
        float4 f4 = ((const float4*)(Ft + r * KDIM))[lane];
        double p0 = a0 * (double)e4.x, p1 = a1 * (double)e4.y;
        double p2 = a2 * (double)e4.z, p3 = a3 * (double)e4.w;
        double s1 = p0 + p1 + p2 + p3;
        double s2 = p0 * (double)f4.x + p1 * (double)f4.y +
                    p2 * (double)f4.z + p3 * (double)f4.w;
        s1 = wave_sum_d(s1);
        s2 = wave_sum_d(s2);
        if (lane == 0) {
          v3s[r] = s1;
          grow[r] = s2 / (16384.0 * s1 * s1);  // gv3~
        }
      }
    }
    __syncthreads();
    if (t < ROWS) wrow[t] = -1.0 / (16384.0 * v3s[t]);
    __syncthreads();
    {
      double ac1 = 0.0, ac2 = 0.0;
#pragma unroll 8
      for (int r = 0; r < ROWS; ++r) {
        double ed = (double)Et[r * KDIM + t];
        ac1 += ed * (double)Ft[r * KDIM + t] * wrow[r];
        ac2 += ed * grow[r];
      }
      unsafeAtomicAdd(&gdirg[t * PAD], ac1);
      unsafeAtomicAdd(&t3g[t * PAD], ac2);
    }
    grid_barrier(bar);

    // ---- Phase D: gu2 -> gv2~ ; accumulate ga2
    {
      double u2v = aload(&u2g[t * PAD]);
      alpha[t] = -(aload(&gdirg[t * PAD]) + aload(&t3g[t * PAD])) * k2_t /
                 (u2v * u2v);
    }
    __syncthreads();
    row_pass(grow);
    __syncthreads();
    if (t < ROWS) wrow[t] = -grow[t] / (16384.0 * v2s[t] * v2s[t]);
    __syncthreads();
    col_accum(ga2g);
    grid_barrier(bar);

    // ---- Phase E: gu1 -> gv1~ ; accumulate ga1
    {
      double u1v = aload(&u1g[t * PAD]);
      alpha[t] = -aload(&ga2g[t * PAD]) * k2_t / (u1v * u1v);
    }
    __syncthreads();
    row_pass(grow);
    __syncthreads();
    if (t < ROWS) wrow[t] = -grow[t] / (16384.0 * v1s[t] * v1s[t]);
    __syncthreads();
    col_accum(ga1g);
    grid_barrier(bar);

    // ---- Phase F: replicated optimizer step (block-local, no barrier)
    {
      double u1v = aload(&u1g[t * PAD]);
      double u2v = aload(&u2g[t * PAD]);
      double gk2 = (aload(&gdirg[t * PAD]) + aload(&t3g[t * PAD])) / u2v +
                   aload(&ga2g[t * PAD]) / u1v + aload(&ga1g[t * PAD]) / u0_t;
      double dot = blk_sum(k2_t * gk2);
      double gw = k2_t * (gk2 - dot) + 5.0 * (k2_t / 256.0 - 1.0 / 65536.0);
      double n2 = blk_sum(gw * gw);
      float normf = (float)sqrt(n2);
      float sc = fminf(1.0f, 1.0f / (normf + 1e-6f));
      float g = (float)gw * sc;
      buf_t = 0.99f * buf_t + g;
      w_t = w_t - 0.1f * buf_t;
      double x = (double)w_t;
      double m = blk_max(x);
      double e = fast_exp_d(x - m);
      double s = blk_sum(e);
      k2_t = e / s;
    }
  }
}

// ---------------------------------------------------------------------------
extern "C" void kernel_launch(void* const* d_in, const int* in_sizes, int n_in,
                              void* d_out, int out_size, void* d_ws,
                              size_t ws_size, hipStream_t stream) {
  (void)in_sizes; (void)n_in; (void)out_size; (void)ws_size;
  const float* feat = (const float*)d_in[0];
  const float* w_in = (const float*)d_in[1];
  float* out = (float*)d_out;
  double* ws = (double*)d_ws;

  kInitWS<<<64, 256, 0, stream>>>(ws);
  sink_main<<<NBLK, 256, 0, stream>>>(feat, w_in, out, ws);
}

// Round 3
// 986.500 us; speedup vs baseline: 1.4776x; 1.4776x over previous
//
#include <hip/hip_runtime.h>

// Balanced sinkhorn, persistent kernel, round 3: replace the contended
// counter barrier (256 serialized RMWs on one line ~28us x48) with a
// contention-free store/poll allreduce:
//   publish: block writes 256-wide f64 partial to own P row + flag1[bid]
//   reduce:  thread t polls flag1[t]; block j sums column j; fin[j]+flag2[j]
//   consume: thread t polls flag2[t]; loads fin[t] (the one value it needs)
// All cross-block data uses agent-scope atomic loads/stores (coherence point,
// no stale-L2 hazard). No RMW atomics anywhere.

namespace {

constexpr int KDIM = 256;
constexpr int NBLK = 256;   // 1 block/CU, all co-resident (LDS-forced)
constexpr int ROWS = 64;    // rows per block
constexpr float L2E20 = 28.853900817779268f;  // 20 * log2(e)

// ws layout (doubles): P[2][256][512] | fin[6][256][16] | flags (u32)
constexpr size_t P_DBL = 2ull * 256 * 512;          // 262144 (2 MB)
constexpr size_t FIN_DBL = 6ull * 256 * 16;         // 24576 (192 KB)
constexpr size_t FLAG_OFF_DBL = P_DBL + FIN_DBL;
constexpr int FLAG_U32 = 2 * 256 * 32;              // flag1+flag2, 128B/line

__device__ __forceinline__ double fast_exp_d(double x) {
  const double LOG2E  = 1.4426950408889634074;
  const double LN2_HI = 6.93147180369123816490e-01;
  const double LN2_LO = 1.90821492927058770002e-10;
  double n = rint(x * LOG2E);
  double t = fma(-n, LN2_HI, x);
  t = fma(-n, LN2_LO, t);
  double p = 2.4801587301587302e-05;
  p = fma(p, t, 1.9841269841269841e-04);
  p = fma(p, t, 1.3888888888888889e-03);
  p = fma(p, t, 8.3333333333333333e-03);
  p = fma(p, t, 4.1666666666666664e-02);
  p = fma(p, t, 1.6666666666666666e-01);
  p = fma(p, t, 0.5);
  p = fma(p, t, 1.0);
  p = fma(p, t, 1.0);
  long long ni = (long long)n;
  double s = __longlong_as_double((unsigned long long)(ni + 1023LL) << 52);
  return p * s;
}

__device__ __forceinline__ double wave_sum_d(double v) {
#pragma unroll
  for (int o = 32; o > 0; o >>= 1) v += __shfl_down(v, o);
  return v;
}
__device__ __forceinline__ double wave_max_d(double v) {
#pragma unroll
  for (int o = 32; o > 0; o >>= 1) v = fmax(v, __shfl_down(v, o));
  return v;
}

__device__ __forceinline__ double pload(const double* p) {
  return __hip_atomic_load(p, __ATOMIC_RELAXED, __HIP_MEMORY_SCOPE_AGENT);
}
__device__ __forceinline__ void pstore(double* p, double v) {
  __hip_atomic_store(p, v, __ATOMIC_RELAXED, __HIP_MEMORY_SCOPE_AGENT);
}

}  // namespace

// ---------------------------------------------------------------------------
__global__ __launch_bounds__(256) void kInitWS(double* __restrict__ ws) {
  unsigned* fl = (unsigned*)(ws + FLAG_OFF_DBL);
  int idx = blockIdx.x * 256 + threadIdx.x;
  if (idx < FLAG_U32) fl[idx] = 0u;
}

// ---------------------------------------------------------------------------
__global__ __launch_bounds__(256, 1) void sink_main(
    const float* __restrict__ feat, const float* __restrict__ w_in,
    float* __restrict__ out, double* __restrict__ ws) {
  __shared__ float  Et[ROWS * KDIM];   // 64 KB
  __shared__ float  Ft[ROWS * KDIM];   // 64 KB
  __shared__ double alpha[KDIM];
  __shared__ double v1s[ROWS], v2s[ROWS], v3s[ROWS];
  __shared__ double grow[ROWS], wrow[ROWS], sbr[ROWS];
  __shared__ float  mrow[ROWS];
  __shared__ double sred[8];

  const int t = threadIdx.x, bid = blockIdx.x;
  const int wv = t >> 6, lane = t & 63;
  const int b0 = bid * ROWS;

  double* P = ws;
  double* fin = ws + P_DBL;
  unsigned* flag1 = (unsigned*)(ws + FLAG_OFF_DBL);
  unsigned* flag2 = flag1 + 256 * 32;

  auto blk_sum = [&](double v) -> double {
    v = wave_sum_d(v);
    __syncthreads();
    if (lane == 0) sred[wv] = v;
    __syncthreads();
    return sred[0] + sred[1] + sred[2] + sred[3];
  };
  auto blk_sum2 = [&](double& a, double& b) {
    a = wave_sum_d(a);
    b = wave_sum_d(b);
    __syncthreads();
    if (lane == 0) { sred[wv] = a; sred[wv + 4] = b; }
    __syncthreads();
    a = sred[0] + sred[1] + sred[2] + sred[3];
    b = sred[4] + sred[5] + sred[6] + sred[7];
  };
  auto blk_max = [&](double v) -> double {
    v = wave_max_d(v);
    __syncthreads();
    if (lane == 0) sred[wv + 4] = v;
    __syncthreads();
    return fmax(fmax(sred[4], sred[5]), fmax(sred[6], sred[7]));
  };

  auto pollf = [&](unsigned* flags, unsigned ph) {
    const unsigned* f = flags + t * 32;
    while (__hip_atomic_load(f, __ATOMIC_RELAXED, __HIP_MEMORY_SCOPE_AGENT) < ph)
      __builtin_amdgcn_s_sleep(4);
  };

  // publish partial(s), column-reduce (block bid owns k=bid), redistribute
  auto publish = [&](unsigned ph, double pa, double pb, bool pair) {
    double* row = P + (((size_t)(ph & 1)) * 256 + bid) * 512;
    pstore(&row[2 * t], pa);
    if (pair) pstore(&row[2 * t + 1], pb);
    __syncthreads();  // drains all threads' stores (vmcnt0 before s_barrier)
    if (t == 0)
      __hip_atomic_store(&flag1[bid * 32], ph, __ATOMIC_RELEASE,
                         __HIP_MEMORY_SCOPE_AGENT);
  };
  auto reduce_col = [&](unsigned ph, int kind, bool pair) {
    pollf(flag1, ph);
    __syncthreads();
    const double* base = P + (((size_t)(ph & 1)) * 256 + t) * 512;
    double c1 = pload(&base[2 * bid]);
    double c2 = 0.0;
    if (pair) {
      c2 = pload(&base[2 * bid + 1]);
      blk_sum2(c1, c2);
    } else {
      c1 = blk_sum(c1);
    }
    if (t == 0) {
      pstore(&fin[(size_t)kind * 4096 + bid * 16], c1);
      if (pair) pstore(&fin[(size_t)kind * 4096 + bid * 16 + 1], c2);
      __hip_atomic_store(&flag2[bid * 32], ph, __ATOMIC_RELEASE,
                         __HIP_MEMORY_SCOPE_AGENT);
    }
    pollf(flag2, ph);
    __syncthreads();
  };
  auto consume1 = [&](int kind) -> double {
    return pload(&fin[(size_t)kind * 4096 + t * 16]);
  };

  auto row_pass = [&](double* dstv) {
    double a0 = alpha[4 * lane + 0], a1 = alpha[4 * lane + 1];
    double a2 = alpha[4 * lane + 2], a3 = alpha[4 * lane + 3];
#pragma unroll 4
    for (int r = wv; r < ROWS; r += 4) {
      float4 e4 = ((const float4*)(Et + r * KDIM))[lane];
      double s1 = a0 * (double)e4.x + a1 * (double)e4.y +
                  a2 * (double)e4.z + a3 * (double)e4.w;
      s1 = wave_sum_d(s1);
      if (lane == 0) dstv[r] = s1;
    }
  };
  auto col_partial = [&]() -> double {
    double a = 0.0;
#pragma unroll 8
    for (int r = 0; r < ROWS; ++r) a += (double)Et[r * KDIM + t] * wrow[r];
    return a;
  };

  // ================= setup =================
  {
    const float4* src = (const float4*)(feat + (size_t)b0 * KDIM);
    float4* dst = (float4*)Ft;
#pragma unroll
    for (int s = 0; s < 16; ++s) dst[s * 256 + t] = src[s * 256 + t];
  }
  __syncthreads();
  for (int r = wv; r < ROWS; r += 4) {
    float4 f4 = ((const float4*)(Ft + r * KDIM))[lane];
    float m = fmaxf(fmaxf(f4.x, f4.y), fmaxf(f4.z, f4.w));
#pragma unroll
    for (int o = 32; o > 0; o >>= 1) m = fmaxf(m, __shfl_down(m, o));
    if (lane == 0) {
      mrow[r] = m;
      sbr[r] = fast_exp_d(20.0 * (double)m);
    }
  }
  __syncthreads();
  double pu0 = 0.0;
#pragma unroll 8
  for (int r = 0; r < ROWS; ++r) {
    float e = exp2f((Ft[r * KDIM + t] - mrow[r]) * L2E20);
    Et[r * KDIM + t] = e;
    pu0 += (double)e * sbr[r];
  }
  float w_t = w_in[t], buf_t = 0.0f;
  double k2_t;
  {
    double x = (double)w_t;
    double m = blk_max(x);
    double e = fast_exp_d(x - m);
    double s = blk_sum(e);
    k2_t = e / s;
  }
  unsigned ph = 1;
  publish(ph, pu0, 0.0, false);
  reduce_col(ph, 0, false);
  const double u0_t = consume1(0);

  // ================= outer loop =================
  for (int it = 0; it < 10; ++it) {
    // ---- A: v1~, allreduce u1
    alpha[t] = k2_t / u0_t;
    __syncthreads();
    row_pass(v1s);
    __syncthreads();
    if (t < ROWS) wrow[t] = 1.0 / (16384.0 * v1s[t]);
    __syncthreads();
    {
      double pa = col_partial();
      ++ph; publish(ph, pa, 0.0, false); reduce_col(ph, 1, false);
    }
    double u1_t = consume1(1);

    // ---- B: v2~, allreduce u2
    alpha[t] = k2_t / u1_t;
    __syncthreads();
    row_pass(v2s);
    __syncthreads();
    if (t < ROWS) wrow[t] = 1.0 / (16384.0 * v2s[t]);
    __syncthreads();
    {
      double pa = col_partial();
      ++ph; publish(ph, pa, 0.0, false); reduce_col(ph, 2, false);
    }
    double u2_t = consume1(2);

    if (it == 9) {
      // ---- output: Q[b,k] = alpha3[k]*E~[r,k]/v3~[b]
      alpha[t] = k2_t / u2_t;
      __syncthreads();
      row_pass(v3s);
      __syncthreads();
      if (t < ROWS) wrow[t] = 1.0 / v3s[t];
      __syncthreads();
      double a3 = alpha[t];
#pragma unroll 4
      for (int r = 0; r < ROWS; ++r)
        out[(size_t)(b0 + r) * KDIM + t] =
            (float)(a3 * (double)Et[r * KDIM + t] * wrow[r]);
      return;
    }

    // ---- C: v3~, gv3~; allreduce (gdir, t3) pair
    alpha[t] = k2_t / u2_t;
    __syncthreads();
    {
      double a0 = alpha[4 * lane + 0], a1 = alpha[4 * lane + 1];
      double a2 = alpha[4 * lane + 2], a3 = alpha[4 * lane + 3];
#pragma unroll 2
      for (int r = wv; r < ROWS; r += 4) {
        float4 e4 = ((const float4*)(Et + r * KDIM))[lane];
        float4 f4 = ((const float4*)(Ft + r * KDIM))[lane];
        double p0 = a0 * (double)e4.x, p1 = a1 * (double)e4.y;
        double p2 = a2 * (double)e4.z, p3 = a3 * (double)e4.w;
        double s1 = p0 + p1 + p2 + p3;
        double s2 = p0 * (double)f4.x + p1 * (double)f4.y +
                    p2 * (double)f4.z + p3 * (double)f4.w;
        s1 = wave_sum_d(s1);
        s2 = wave_sum_d(s2);
        if (lane == 0) {
          v3s[r] = s1;
          grow[r] = s2 / (16384.0 * s1 * s1);  // gv3~
        }
      }
    }
    __syncthreads();
    if (t < ROWS) wrow[t] = -1.0 / (16384.0 * v3s[t]);
    __syncthreads();
    {
      double ac1 = 0.0, ac2 = 0.0;
#pragma unroll 8
      for (int r = 0; r < ROWS; ++r) {
        double ed = (double)Et[r * KDIM + t];
        ac1 += ed * (double)Ft[r * KDIM + t] * wrow[r];
        ac2 += ed * grow[r];
      }
      ++ph; publish(ph, ac1, ac2, true); reduce_col(ph, 3, true);
    }
    double gd_t = pload(&fin[3 * 4096 + t * 16]);
    double t3_t = pload(&fin[3 * 4096 + t * 16 + 1]);

    // ---- D: gu2 -> gv2~; allreduce ga2
    alpha[t] = -(gd_t + t3_t) * k2_t / (u2_t * u2_t);
    __syncthreads();
    row_pass(grow);
    __syncthreads();
    if (t < ROWS) wrow[t] = -grow[t] / (16384.0 * v2s[t] * v2s[t]);
    __syncthreads();
    {
      double pa = col_partial();
      ++ph; publish(ph, pa, 0.0, false); reduce_col(ph, 4, false);
    }
    double ga2_t = consume1(4);

    // ---- E: gu1 -> gv1~; allreduce ga1
    alpha[t] = -ga2_t * k2_t / (u1_t * u1_t);
    __syncthreads();
    row_pass(grow);
    __syncthreads();
    if (t < ROWS) wrow[t] = -grow[t] / (16384.0 * v1s[t] * v1s[t]);
    __syncthreads();
    {
      double pa = col_partial();
      ++ph; publish(ph, pa, 0.0, false); reduce_col(ph, 5, false);
    }
    double ga1_t = consume1(5);

    // ---- F: replicated optimizer step (block-local)
    {
      double gk2 = (gd_t + t3_t) / u2_t + ga2_t / u1_t + ga1_t / u0_t;
      double dot = blk_sum(k2_t * gk2);
      double gw = k2_t * (gk2 - dot) + 5.0 * (k2_t / 256.0 - 1.0 / 65536.0);
      double n2 = blk_sum(gw * gw);
      float normf = (float)sqrt(n2);
      float sc = fminf(1.0f, 1.0f / (normf + 1e-6f));
      float g = (float)gw * sc;
      buf_t = 0.99f * buf_t + g;
      w_t = w_t - 0.1f * buf_t;
      double x = (double)w_t;
      double m = blk_max(x);
      double e = fast_exp_d(x - m);
      double s = blk_sum(e);
      k2_t = e / s;
    }
  }
}

// ---------------------------------------------------------------------------
extern "C" void kernel_launch(void* const* d_in, const int* in_sizes, int n_in,
                              void* d_out, int out_size, void* d_ws,
                              size_t ws_size, hipStream_t stream) {
  (void)in_sizes; (void)n_in; (void)out_size; (void)ws_size;
  const float* feat = (const float*)d_in[0];
  const float* w_in = (const float*)d_in[1];
  float* out = (float*)d_out;
  double* ws = (double*)d_ws;

  kInitWS<<<64, 256, 0, stream>>>(ws);
  sink_main<<<NBLK, 256, 0, stream>>>(feat, w_in, out, ws);
}

// Round 4
// 694.253 us; speedup vs baseline: 2.0996x; 1.4210x over previous
//
#include <hip/hip_runtime.h>

// Balanced sinkhorn, persistent kernel, round 4: decongested allreduce.
// Round-3 post-mortem: 65536 pollers => 256 same-line readers per flag line
// => serialized LLC reads => ~9us/hop. Fix: 16 reducer blocks (16 readers per
// publisher flag line) + 16 replicas of each reducer-done flag (16 readers per
// line on the consumer side). Phase math / LDS tiles / replicated optimizer
// identical to round 3 (validated, absmax 2.4e-4).

namespace {

constexpr int KDIM = 256;
constexpr int NBLK = 256;   // 1 block/CU, all co-resident (LDS-forced)
constexpr int ROWS = 64;    // rows per block
constexpr int NRED = 16;    // reducer blocks
constexpr float L2E20 = 28.853900817779268f;  // 20 * log2(e)

// ws layout (doubles): P[2][256][512] | fin[6][256][2] (pad 4096) | flags
constexpr size_t P_DBL = 2ull * 256 * 512;     // 262144 doubles (2 MB)
constexpr size_t FIN_OFF = P_DBL;              // 6*512 = 3072 used, 4096 rsvd
constexpr size_t FLAG_OFF_DBL = P_DBL + 4096;
constexpr int FLAG_U32 = 16384;                // flag1[256][32] + flag2R[256][32]

__device__ __forceinline__ double fast_exp_d(double x) {
  const double LOG2E  = 1.4426950408889634074;
  const double LN2_HI = 6.93147180369123816490e-01;
  const double LN2_LO = 1.90821492927058770002e-10;
  double n = rint(x * LOG2E);
  double t = fma(-n, LN2_HI, x);
  t = fma(-n, LN2_LO, t);
  double p = 2.4801587301587302e-05;
  p = fma(p, t, 1.9841269841269841e-04);
  p = fma(p, t, 1.3888888888888889e-03);
  p = fma(p, t, 8.3333333333333333e-03);
  p = fma(p, t, 4.1666666666666664e-02);
  p = fma(p, t, 1.6666666666666666e-01);
  p = fma(p, t, 0.5);
  p = fma(p, t, 1.0);
  p = fma(p, t, 1.0);
  long long ni = (long long)n;
  double s = __longlong_as_double((unsigned long long)(ni + 1023LL) << 52);
  return p * s;
}

__device__ __forceinline__ double wave_sum_d(double v) {
#pragma unroll
  for (int o = 32; o > 0; o >>= 1) v += __shfl_down(v, o);
  return v;
}
__device__ __forceinline__ double wave_max_d(double v) {
#pragma unroll
  for (int o = 32; o > 0; o >>= 1) v = fmax(v, __shfl_down(v, o));
  return v;
}

__device__ __forceinline__ double pload(const double* p) {
  return __hip_atomic_load(p, __ATOMIC_RELAXED, __HIP_MEMORY_SCOPE_AGENT);
}
__device__ __forceinline__ void pstore(double* p, double v) {
  __hip_atomic_store(p, v, __ATOMIC_RELAXED, __HIP_MEMORY_SCOPE_AGENT);
}

}  // namespace

// ---------------------------------------------------------------------------
__global__ __launch_bounds__(256) void kInitWS(double* __restrict__ ws) {
  unsigned* fl = (unsigned*)(ws + FLAG_OFF_DBL);
  int idx = blockIdx.x * 256 + threadIdx.x;
  if (idx < FLAG_U32) fl[idx] = 0u;
}

// ---------------------------------------------------------------------------
__global__ __launch_bounds__(256, 1) void sink_main(
    const float* __restrict__ feat, const float* __restrict__ w_in,
    float* __restrict__ out, double* __restrict__ ws) {
  __shared__ float  Et[ROWS * KDIM];   // 64 KB
  __shared__ float  Ft[ROWS * KDIM];   // 64 KB
  __shared__ double alpha[KDIM];
  __shared__ double tmp1[KDIM];        // reducer stage-2 fold
  __shared__ double tmp2[KDIM];
  __shared__ double v1s[ROWS], v2s[ROWS], v3s[ROWS];
  __shared__ double grow[ROWS], wrow[ROWS], sbr[ROWS];
  __shared__ float  mrow[ROWS];
  __shared__ double sred[8];

  const int t = threadIdx.x, bid = blockIdx.x;
  const int wv = t >> 6, lane = t & 63;
  const int b0 = bid * ROWS;

  double* P = ws;
  double* fin = ws + FIN_OFF;
  unsigned* flag1 = (unsigned*)(ws + FLAG_OFF_DBL);  // [256][32] u32
  unsigned* flag2 = flag1 + 8192;                    // [16*16][32] replicas

  auto blk_sum = [&](double v) -> double {
    v = wave_sum_d(v);
    __syncthreads();
    if (lane == 0) sred[wv] = v;
    __syncthreads();
    return sred[0] + sred[1] + sred[2] + sred[3];
  };
  auto blk_max = [&](double v) -> double {
    v = wave_max_d(v);
    __syncthreads();
    if (lane == 0) sred[wv + 4] = v;
    __syncthreads();
    return fmax(fmax(sred[4], sred[5]), fmax(sred[6], sred[7]));
  };

  // ---- decongested allreduce over k=0..255 (optionally a pair per k)
  auto allreduce = [&](unsigned ph, int kind, bool pair, double pa, double pb) {
    // publish: own P row + own flag line (16 reader blocks per line)
    double* row = P + (((size_t)(ph & 1)) * 256 + bid) * 512;
    pstore(&row[2 * t], pa);
    if (pair) pstore(&row[2 * t + 1], pb);
    __syncthreads();  // s_barrier drains vmcnt -> stores at coherence point
    if (t == 0)
      __hip_atomic_store(&flag1[bid * 32], ph, __ATOMIC_RELEASE,
                         __HIP_MEMORY_SCOPE_AGENT);
    // stage 2: 16 reducer blocks; block j owns k in [j*16, j*16+16)
    if (bid < NRED) {
      {
        const unsigned* f = &flag1[t * 32];
        while (__hip_atomic_load(f, __ATOMIC_RELAXED,
                                 __HIP_MEMORY_SCOPE_AGENT) < ph)
          __builtin_amdgcn_s_sleep(2);
      }
      __syncthreads();
      const double* base = P + ((size_t)(ph & 1)) * 131072;
      int g = t >> 4, c = t & 15;
      int k = bid * 16 + c;
      double a1 = 0.0, a2 = 0.0;
#pragma unroll
      for (int i = 0; i < 16; ++i) {
        const double* rr = base + (size_t)(g + 16 * i) * 512;
        a1 += pload(&rr[2 * k]);
        if (pair) a2 += pload(&rr[2 * k + 1]);
      }
      tmp1[t] = a1;
      if (pair) tmp2[t] = a2;
      __syncthreads();
      if (t < 16) {
        double s = 0.0;
#pragma unroll
        for (int g2 = 0; g2 < 16; ++g2) s += tmp1[g2 * 16 + t];
        pstore(&fin[(size_t)kind * 512 + (size_t)(bid * 16 + t) * 2], s);
      } else if (pair && t < 32) {
        int c2 = t - 16;
        double s = 0.0;
#pragma unroll
        for (int g2 = 0; g2 < 16; ++g2) s += tmp2[g2 * 16 + c2];
        pstore(&fin[(size_t)kind * 512 + (size_t)(bid * 16 + c2) * 2 + 1], s);
      }
      __syncthreads();  // drain fin stores
      if (t < 16)       // 16 replicas of "reducer bid done", own lines
        __hip_atomic_store(&flag2[(bid * 16 + t) * 32], ph, __ATOMIC_RELEASE,
                           __HIP_MEMORY_SCOPE_AGENT);
    }
    // consume wait: thread t<16 polls reducer t's replica #(bid&15)
    if (t < 16) {
      const unsigned* f = &flag2[(t * 16 + (bid & 15)) * 32];
      while (__hip_atomic_load(f, __ATOMIC_RELAXED,
                               __HIP_MEMORY_SCOPE_AGENT) < ph)
        __builtin_amdgcn_s_sleep(2);
    }
    __syncthreads();
  };

  auto row_pass = [&](double* dstv) {
    double a0 = alpha[4 * lane + 0], a1 = alpha[4 * lane + 1];
    double a2 = alpha[4 * lane + 2], a3 = alpha[4 * lane + 3];
#pragma unroll 4
    for (int r = wv; r < ROWS; r += 4) {
      float4 e4 = ((const float4*)(Et + r * KDIM))[lane];
      double s1 = a0 * (double)e4.x + a1 * (double)e4.y +
                  a2 * (double)e4.z + a3 * (double)e4.w;
      s1 = wave_sum_d(s1);
      if (lane == 0) dstv[r] = s1;
    }
  };
  auto col_partial = [&]() -> double {
    double a = 0.0;
#pragma unroll 8
    for (int r = 0; r < ROWS; ++r) a += (double)Et[r * KDIM + t] * wrow[r];
    return a;
  };

  // ================= setup =================
  {
    const float4* src = (const float4*)(feat + (size_t)b0 * KDIM);
    float4* dst = (float4*)Ft;
#pragma unroll
    for (int s = 0; s < 16; ++s) dst[s * 256 + t] = src[s * 256 + t];
  }
  __syncthreads();
  for (int r = wv; r < ROWS; r += 4) {
    float4 f4 = ((const float4*)(Ft + r * KDIM))[lane];
    float m = fmaxf(fmaxf(f4.x, f4.y), fmaxf(f4.z, f4.w));
#pragma unroll
    for (int o = 32; o > 0; o >>= 1) m = fmaxf(m, __shfl_down(m, o));
    if (lane == 0) {
      mrow[r] = m;
      sbr[r] = fast_exp_d(20.0 * (double)m);
    }
  }
  __syncthreads();
  double pu0 = 0.0;
#pragma unroll 8
  for (int r = 0; r < ROWS; ++r) {
    float e = exp2f((Ft[r * KDIM + t] - mrow[r]) * L2E20);
    Et[r * KDIM + t] = e;
    pu0 += (double)e * sbr[r];
  }
  float w_t = w_in[t], buf_t = 0.0f;
  double k2_t;
  {
    double x = (double)w_t;
    double m = blk_max(x);
    double e = fast_exp_d(x - m);
    double s = blk_sum(e);
    k2_t = e / s;
  }
  unsigned ph = 1;
  allreduce(ph, 0, false, pu0, 0.0);
  const double u0_t = pload(&fin[0 * 512 + 2 * t]);

  // ================= outer loop =================
  for (int it = 0; it < 10; ++it) {
    // ---- A: v1~, allreduce u1
    alpha[t] = k2_t / u0_t;
    __syncthreads();
    row_pass(v1s);
    __syncthreads();
    if (t < ROWS) wrow[t] = 1.0 / (16384.0 * v1s[t]);
    __syncthreads();
    {
      double pa = col_partial();
      ++ph; allreduce(ph, 1, false, pa, 0.0);
    }
    double u1_t = pload(&fin[1 * 512 + 2 * t]);

    // ---- B: v2~, allreduce u2
    alpha[t] = k2_t / u1_t;
    __syncthreads();
    row_pass(v2s);
    __syncthreads();
    if (t < ROWS) wrow[t] = 1.0 / (16384.0 * v2s[t]);
    __syncthreads();
    {
      double pa = col_partial();
      ++ph; allreduce(ph, 2, false, pa, 0.0);
    }
    double u2_t = pload(&fin[2 * 512 + 2 * t]);

    if (it == 9) {
      // ---- output: Q[b,k] = alpha3[k]*E~[r,k]/v3~[b]
      alpha[t] = k2_t / u2_t;
      __syncthreads();
      row_pass(v3s);
      __syncthreads();
      if (t < ROWS) wrow[t] = 1.0 / v3s[t];
      __syncthreads();
      double a3 = alpha[t];
#pragma unroll 4
      for (int r = 0; r < ROWS; ++r)
        out[(size_t)(b0 + r) * KDIM + t] =
            (float)(a3 * (double)Et[r * KDIM + t] * wrow[r]);
      return;
    }

    // ---- C: v3~, gv3~; allreduce (gdir, t3) pair
    alpha[t] = k2_t / u2_t;
    __syncthreads();
    {
      double a0 = alpha[4 * lane + 0], a1 = alpha[4 * lane + 1];
      double a2 = alpha[4 * lane + 2], a3 = alpha[4 * lane + 3];
#pragma unroll 2
      for (int r = wv; r < ROWS; r += 4) {
        float4 e4 = ((const float4*)(Et + r * KDIM))[lane];
        float4 f4 = ((const float4*)(Ft + r * KDIM))[lane];
        double p0 = a0 * (double)e4.x, p1 = a1 * (double)e4.y;
        double p2 = a2 * (double)e4.z, p3 = a3 * (double)e4.w;
        double s1 = p0 + p1 + p2 + p3;
        double s2 = p0 * (double)f4.x + p1 * (double)f4.y +
                    p2 * (double)f4.z + p3 * (double)f4.w;
        s1 = wave_sum_d(s1);
        s2 = wave_sum_d(s2);
        if (lane == 0) {
          v3s[r] = s1;
          grow[r] = s2 / (16384.0 * s1 * s1);  // gv3~
        }
      }
    }
    __syncthreads();
    if (t < ROWS) wrow[t] = -1.0 / (16384.0 * v3s[t]);
    __syncthreads();
    {
      double ac1 = 0.0, ac2 = 0.0;
#pragma unroll 8
      for (int r = 0; r < ROWS; ++r) {
        double ed = (double)Et[r * KDIM + t];
        ac1 += ed * (double)Ft[r * KDIM + t] * wrow[r];
        ac2 += ed * grow[r];
      }
      ++ph; allreduce(ph, 3, true, ac1, ac2);
    }
    double gd_t = pload(&fin[3 * 512 + 2 * t]);
    double t3_t = pload(&fin[3 * 512 + 2 * t + 1]);

    // ---- D: gu2 -> gv2~; allreduce ga2
    alpha[t] = -(gd_t + t3_t) * k2_t / (u2_t * u2_t);
    __syncthreads();
    row_pass(grow);
    __syncthreads();
    if (t < ROWS) wrow[t] = -grow[t] / (16384.0 * v2s[t] * v2s[t]);
    __syncthreads();
    {
      double pa = col_partial();
      ++ph; allreduce(ph, 4, false, pa, 0.0);
    }
    double ga2_t = pload(&fin[4 * 512 + 2 * t]);

    // ---- E: gu1 -> gv1~; allreduce ga1
    alpha[t] = -ga2_t * k2_t / (u1_t * u1_t);
    __syncthreads();
    row_pass(grow);
    __syncthreads();
    if (t < ROWS) wrow[t] = -grow[t] / (16384.0 * v1s[t] * v1s[t]);
    __syncthreads();
    {
      double pa = col_partial();
      ++ph; allreduce(ph, 5, false, pa, 0.0);
    }
    double ga1_t = pload(&fin[5 * 512 + 2 * t]);

    // ---- F: replicated optimizer step (block-local)
    {
      double gk2 = (gd_t + t3_t) / u2_t + ga2_t / u1_t + ga1_t / u0_t;
      double dot = blk_sum(k2_t * gk2);
      double gw = k2_t * (gk2 - dot) + 5.0 * (k2_t / 256.0 - 1.0 / 65536.0);
      double n2 = blk_sum(gw * gw);
      float normf = (float)sqrt(n2);
      float sc = fminf(1.0f, 1.0f / (normf + 1e-6f));
      float g = (float)gw * sc;
      buf_t = 0.99f * buf_t + g;
      w_t = w_t - 0.1f * buf_t;
      double x = (double)w_t;
      double m = blk_max(x);
      double e = fast_exp_d(x - m);
      double s = blk_sum(e);
      k2_t = e / s;
    }
  }
}

// ---------------------------------------------------------------------------
extern "C" void kernel_launch(void* const* d_in, const int* in_sizes, int n_in,
                              void* d_out, int out_size, void* d_ws,
                              size_t ws_size, hipStream_t stream) {
  (void)in_sizes; (void)n_in; (void)out_size; (void)ws_size;
  const float* feat = (const float*)d_in[0];
  const float* w_in = (const float*)d_in[1];
  float* out = (float*)d_out;
  double* ws = (double*)d_ws;

  kInitWS<<<64, 256, 0, stream>>>(ws);
  sink_main<<<NBLK, 256, 0, stream>>>(feat, w_in, out, ws);
}

// Round 5
// 558.112 us; speedup vs baseline: 2.6117x; 1.2439x over previous
//
#include <hip/hip_runtime.h>

// Balanced sinkhorn, persistent kernel, round 5.
// R4 post-mortem: fin consume-read had 256 same-line readers (~5us) and
// RELEASE flag stores may emit L2 writebacks. Fixes:
//  - fin replicated x16 (reader fan-out 256 -> 16 blocks/line)
//  - flag2 removed: consumers value-poll fin with qNaN sentinel (reducers
//    refresh the other-parity copy, ordering via syncthreads vmcnt drains)
//  - all atomics RELAXED agent-scope; ordering from vmcnt(0) drains only.
// Phase math / LDS tiles / replicated optimizer identical to R3/R4
// (validated, absmax 2.4e-4).

namespace {

constexpr int KDIM = 256;
constexpr int NBLK = 256;   // 1 block/CU, all co-resident (LDS-forced)
constexpr int ROWS = 64;    // rows per block
constexpr int NRED = 16;    // reducer blocks
constexpr float L2E20 = 28.853900817779268f;  // 20 * log2(e)

// ws layout (doubles):
//   P[2][256][512]                          262144 dbl (2 MB)
//   fin[2][6][16 reps][256 k][2]             98304 dbl (768 KB)
//   flag1[256][32] u32                       32 KB
constexpr size_t P_DBL   = 2ull * 256 * 512;   // 262144
constexpr size_t FIN_OFF = P_DBL;
constexpr size_t FIN_PAR = 6ull * 16 * 256 * 2;  // 49152 dbl per parity
constexpr size_t FIN_DBL = 2 * FIN_PAR;          // 98304
constexpr size_t FLAG_OFF_DBL = FIN_OFF + FIN_DBL;  // 360448
constexpr int FLAG_U32 = 256 * 32;

__device__ __forceinline__ double fast_exp_d(double x) {
  const double LOG2E  = 1.4426950408889634074;
  const double LN2_HI = 6.93147180369123816490e-01;
  const double LN2_LO = 1.90821492927058770002e-10;
  double n = rint(x * LOG2E);
  double t = fma(-n, LN2_HI, x);
  t = fma(-n, LN2_LO, t);
  double p = 2.4801587301587302e-05;
  p = fma(p, t, 1.9841269841269841e-04);
  p = fma(p, t, 1.3888888888888889e-03);
  p = fma(p, t, 8.3333333333333333e-03);
  p = fma(p, t, 4.1666666666666664e-02);
  p = fma(p, t, 1.6666666666666666e-01);
  p = fma(p, t, 0.5);
  p = fma(p, t, 1.0);
  p = fma(p, t, 1.0);
  long long ni = (long long)n;
  double s = __longlong_as_double((unsigned long long)(ni + 1023LL) << 52);
  return p * s;
}

__device__ __forceinline__ double wave_sum_d(double v) {
#pragma unroll
  for (int o = 32; o > 0; o >>= 1) v += __shfl_down(v, o);
  return v;
}
__device__ __forceinline__ double wave_max_d(double v) {
#pragma unroll
  for (int o = 32; o > 0; o >>= 1) v = fmax(v, __shfl_down(v, o));
  return v;
}

__device__ __forceinline__ double pload(const double* p) {
  return __hip_atomic_load(p, __ATOMIC_RELAXED, __HIP_MEMORY_SCOPE_AGENT);
}
__device__ __forceinline__ void pstore(double* p, double v) {
  __hip_atomic_store(p, v, __ATOMIC_RELAXED, __HIP_MEMORY_SCOPE_AGENT);
}

}  // namespace

// ---------------------------------------------------------------------------
__global__ __launch_bounds__(256) void kInitWS(double* __restrict__ ws) {
  const double QN = __builtin_nan("");
  size_t gid = (size_t)blockIdx.x * 256 + threadIdx.x;
  size_t stride = (size_t)gridDim.x * 256;
  double* fin = ws + FIN_OFF;
  for (size_t j = gid; j < FIN_DBL; j += stride) fin[j] = QN;
  unsigned* fl = (unsigned*)(ws + FLAG_OFF_DBL);
  if (gid < FLAG_U32) fl[gid] = 0u;
}

// ---------------------------------------------------------------------------
__global__ __launch_bounds__(256, 1) void sink_main(
    const float* __restrict__ feat, const float* __restrict__ w_in,
    float* __restrict__ out, double* __restrict__ ws) {
  __shared__ float  Et[ROWS * KDIM];   // 64 KB
  __shared__ float  Ft[ROWS * KDIM];   // 64 KB
  __shared__ double alpha[KDIM];
  __shared__ double tmp1[KDIM];        // reducer stage-2 fold
  __shared__ double tmp2[KDIM];
  __shared__ double sfin[32];          // reducer folded (16 k x 2)
  __shared__ double v1s[ROWS], v2s[ROWS], v3s[ROWS];
  __shared__ double grow[ROWS], wrow[ROWS], sbr[ROWS];
  __shared__ float  mrow[ROWS];
  __shared__ double sred[8];

  const int t = threadIdx.x, bid = blockIdx.x;
  const int wv = t >> 6, lane = t & 63;
  const int b0 = bid * ROWS;
  const double QN = __builtin_nan("");

  double* P = ws;
  double* fin = ws + FIN_OFF;
  unsigned* flag1 = (unsigned*)(ws + FLAG_OFF_DBL);  // [256][32] u32

  auto blk_sum = [&](double v) -> double {
    v = wave_sum_d(v);
    __syncthreads();
    if (lane == 0) sred[wv] = v;
    __syncthreads();
    return sred[0] + sred[1] + sred[2] + sred[3];
  };
  auto blk_max = [&](double v) -> double {
    v = wave_max_d(v);
    __syncthreads();
    if (lane == 0) sred[wv + 4] = v;
    __syncthreads();
    return fmax(fmax(sred[4], sred[5]), fmax(sred[6], sred[7]));
  };

  // ---- allreduce over k=0..255 (optionally a value pair per k).
  // Results for k=t land in r1/r2. par selects the fin parity copy.
  auto allreduce = [&](unsigned ph, int kind, bool pair, int par,
                       double pa, double pb, double& r1, double& r2) {
    // publish: own P row; flag after syncthreads (vmcnt(0) drained)
    double* row = P + (((size_t)(ph & 1)) * 256 + bid) * 512;
    pstore(&row[2 * t], pa);
    if (pair) pstore(&row[2 * t + 1], pb);
    __syncthreads();
    if (t == 0)
      __hip_atomic_store(&flag1[bid * 32], ph, __ATOMIC_RELAXED,
                         __HIP_MEMORY_SCOPE_AGENT);
    if (bid < NRED) {
      const int rep = t >> 4, c = t & 15;
      // refresh other-parity sentinel (consumed >= 1 full allreduce ago;
      // visibility before next use ordered by intervening vmcnt drains)
      {
        double* dst = fin + (size_t)(1 - par) * FIN_PAR +
                      (size_t)kind * 8192 + (size_t)rep * 512 +
                      2 * (size_t)(bid * 16 + c);
        pstore(dst, QN);
        pstore(dst + 1, QN);
      }
      // wait for all publishers (16 reader blocks per flag line)
      {
        const unsigned* f = &flag1[t * 32];
        while (__hip_atomic_load(f, __ATOMIC_RELAXED,
                                 __HIP_MEMORY_SCOPE_AGENT) < ph)
          __builtin_amdgcn_s_sleep(1);
      }
      __syncthreads();
      // column reduce: thread (g,c) sums rows g+16i for k=bid*16+c
      const double* base = P + ((size_t)(ph & 1)) * 131072;
      const int k = bid * 16 + c;
      double a1 = 0.0, a2 = 0.0;
#pragma unroll
      for (int i = 0; i < 16; ++i) {
        const double* rr = base + (size_t)(rep + 16 * i) * 512;
        a1 += pload(&rr[2 * k]);
        if (pair) a2 += pload(&rr[2 * k + 1]);
      }
      tmp1[t] = a1;
      if (pair) tmp2[t] = a2;
      __syncthreads();
      if (t < 16) {
        double s = 0.0;
#pragma unroll
        for (int g2 = 0; g2 < 16; ++g2) s += tmp1[g2 * 16 + t];
        sfin[2 * t] = s;
        if (!pair) sfin[2 * t + 1] = 0.0;
      } else if (pair && t < 32) {
        int c2 = t - 16;
        double s = 0.0;
#pragma unroll
        for (int g2 = 0; g2 < 16; ++g2) s += tmp2[g2 * 16 + c2];
        sfin[2 * c2 + 1] = s;
      }
      __syncthreads();
      // replicate x16: one entry per thread
      {
        double* dst = fin + (size_t)par * FIN_PAR + (size_t)kind * 8192 +
                      (size_t)rep * 512 + 2 * (size_t)(bid * 16 + c);
        pstore(dst, sfin[2 * c]);
        if (pair) pstore(dst + 1, sfin[2 * c + 1]);
      }
    }
    // consume: value-poll own entry in own replica
    {
      const double* e = fin + (size_t)par * FIN_PAR + (size_t)kind * 8192 +
                        (size_t)(bid & 15) * 512 + 2 * (size_t)t;
      double a;
      for (;;) {
        a = pload(e);
        if (!__builtin_isnan(a)) break;
        __builtin_amdgcn_s_sleep(1);
      }
      r1 = a;
      if (pair) {
        double b;
        for (;;) {
          b = pload(e + 1);
          if (!__builtin_isnan(b)) break;
          __builtin_amdgcn_s_sleep(1);
        }
        r2 = b;
      }
    }
    __syncthreads();
  };

  auto row_pass = [&](double* dstv) {
    double a0 = alpha[4 * lane + 0], a1 = alpha[4 * lane + 1];
    double a2 = alpha[4 * lane + 2], a3 = alpha[4 * lane + 3];
#pragma unroll 4
    for (int r = wv; r < ROWS; r += 4) {
      float4 e4 = ((const float4*)(Et + r * KDIM))[lane];
      double s1 = a0 * (double)e4.x + a1 * (double)e4.y +
                  a2 * (double)e4.z + a3 * (double)e4.w;
      s1 = wave_sum_d(s1);
      if (lane == 0) dstv[r] = s1;
    }
  };
  auto col_partial = [&]() -> double {
    double a = 0.0;
#pragma unroll 8
    for (int r = 0; r < ROWS; ++r) a += (double)Et[r * KDIM + t] * wrow[r];
    return a;
  };

  // ================= setup =================
  {
    const float4* src = (const float4*)(feat + (size_t)b0 * KDIM);
    float4* dst = (float4*)Ft;
#pragma unroll
    for (int s = 0; s < 16; ++s) dst[s * 256 + t] = src[s * 256 + t];
  }
  __syncthreads();
  for (int r = wv; r < ROWS; r += 4) {
    float4 f4 = ((const float4*)(Ft + r * KDIM))[lane];
    float m = fmaxf(fmaxf(f4.x, f4.y), fmaxf(f4.z, f4.w));
#pragma unroll
    for (int o = 32; o > 0; o >>= 1) m = fmaxf(m, __shfl_down(m, o));
    if (lane == 0) {
      mrow[r] = m;
      sbr[r] = fast_exp_d(20.0 * (double)m);
    }
  }
  __syncthreads();
  double pu0 = 0.0;
#pragma unroll 8
  for (int r = 0; r < ROWS; ++r) {
    float e = exp2f((Ft[r * KDIM + t] - mrow[r]) * L2E20);
    Et[r * KDIM + t] = e;
    pu0 += (double)e * sbr[r];
  }
  float w_t = w_in[t], buf_t = 0.0f;
  double k2_t;
  {
    double x = (double)w_t;
    double m = blk_max(x);
    double e = fast_exp_d(x - m);
    double s = blk_sum(e);
    k2_t = e / s;
  }
  unsigned ph = 1;
  double u0_t, dmy;
  allreduce(ph, 0, false, 0, pu0, 0.0, u0_t, dmy);

  // ================= outer loop =================
  for (int it = 0; it < 10; ++it) {
    const int p = it & 1;
    double u1_t, u2_t;

    // ---- A: v1~, allreduce u1
    alpha[t] = k2_t / u0_t;
    __syncthreads();
    row_pass(v1s);
    __syncthreads();
    if (t < ROWS) wrow[t] = 1.0 / (16384.0 * v1s[t]);
    __syncthreads();
    {
      double pa = col_partial();
      ++ph; allreduce(ph, 1, false, p, pa, 0.0, u1_t, dmy);
    }

    // ---- B: v2~, allreduce u2
    alpha[t] = k2_t / u1_t;
    __syncthreads();
    row_pass(v2s);
    __syncthreads();
    if (t < ROWS) wrow[t] = 1.0 / (16384.0 * v2s[t]);
    __syncthreads();
    {
      double pa = col_partial();
      ++ph; allreduce(ph, 2, false, p, pa, 0.0, u2_t, dmy);
    }

    if (it == 9) {
      // ---- output: Q[b,k] = alpha3[k]*E~[r,k]/v3~[b]
      alpha[t] = k2_t / u2_t;
      __syncthreads();
      row_pass(v3s);
      __syncthreads();
      if (t < ROWS) wrow[t] = 1.0 / v3s[t];
      __syncthreads();
      double a3 = alpha[t];
#pragma unroll 4
      for (int r = 0; r < ROWS; ++r)
        out[(size_t)(b0 + r) * KDIM + t] =
            (float)(a3 * (double)Et[r * KDIM + t] * wrow[r]);
      return;
    }

    // ---- C: v3~, gv3~; allreduce (gdir, t3) pair
    alpha[t] = k2_t / u2_t;
    __syncthreads();
    {
      double a0 = alpha[4 * lane + 0], a1 = alpha[4 * lane + 1];
      double a2 = alpha[4 * lane + 2], a3 = alpha[4 * lane + 3];
#pragma unroll 2
      for (int r = wv; r < ROWS; r += 4) {
        float4 e4 = ((const float4*)(Et + r * KDIM))[lane];
        float4 f4 = ((const float4*)(Ft + r * KDIM))[lane];
        double p0 = a0 * (double)e4.x, p1 = a1 * (double)e4.y;
        double p2 = a2 * (double)e4.z, p3 = a3 * (double)e4.w;
        double s1 = p0 + p1 + p2 + p3;
        double s2 = p0 * (double)f4.x + p1 * (double)f4.y +
                    p2 * (double)f4.z + p3 * (double)f4.w;
        s1 = wave_sum_d(s1);
        s2 = wave_sum_d(s2);
        if (lane == 0) {
          v3s[r] = s1;
          grow[r] = s2 / (16384.0 * s1 * s1);  // gv3~
        }
      }
    }
    __syncthreads();
    if (t < ROWS) wrow[t] = -1.0 / (16384.0 * v3s[t]);
    __syncthreads();
    double gd_t, t3_t;
    {
      double ac1 = 0.0, ac2 = 0.0;
#pragma unroll 8
      for (int r = 0; r < ROWS; ++r) {
        double ed = (double)Et[r * KDIM + t];
        ac1 += ed * (double)Ft[r * KDIM + t] * wrow[r];
        ac2 += ed * grow[r];
      }
      ++ph; allreduce(ph, 3, true, p, ac1, ac2, gd_t, t3_t);
    }

    // ---- D: gu2 -> gv2~; allreduce ga2
    alpha[t] = -(gd_t + t3_t) * k2_t / (u2_t * u2_t);
    __syncthreads();
    row_pass(grow);
    __syncthreads();
    if (t < ROWS) wrow[t] = -grow[t] / (16384.0 * v2s[t] * v2s[t]);
    __syncthreads();
    double ga2_t;
    {
      double pa = col_partial();
      ++ph; allreduce(ph, 4, false, p, pa, 0.0, ga2_t, dmy);
    }

    // ---- E: gu1 -> gv1~; allreduce ga1
    alpha[t] = -ga2_t * k2_t / (u1_t * u1_t);
    __syncthreads();
    row_pass(grow);
    __syncthreads();
    if (t < ROWS) wrow[t] = -grow[t] / (16384.0 * v1s[t] * v1s[t]);
    __syncthreads();
    double ga1_t;
    {
      double pa = col_partial();
      ++ph; allreduce(ph, 5, false, p, pa, 0.0, ga1_t, dmy);
    }

    // ---- F: replicated optimizer step (block-local)
    {
      double gk2 = (gd_t + t3_t) / u2_t + ga2_t / u1_t + ga1_t / u0_t;
      double dot = blk_sum(k2_t * gk2);
      double gw = k2_t * (gk2 - dot) + 5.0 * (k2_t / 256.0 - 1.0 / 65536.0);
      double n2 = blk_sum(gw * gw);
      float normf = (float)sqrt(n2);
      float sc = fminf(1.0f, 1.0f / (normf + 1e-6f));
      float g = (float)gw * sc;
      buf_t = 0.99f * buf_t + g;
      w_t = w_t - 0.1f * buf_t;
      double x = (double)w_t;
      double m = blk_max(x);
      double e = fast_exp_d(x - m);
      double s = blk_sum(e);
      k2_t = e / s;
    }
  }
}

// ---------------------------------------------------------------------------
extern "C" void kernel_launch(void* const* d_in, const int* in_sizes, int n_in,
                              void* d_out, int out_size, void* d_ws,
                              size_t ws_size, hipStream_t stream) {
  (void)in_sizes; (void)n_in; (void)out_size; (void)ws_size;
  const float* feat = (const float*)d_in[0];
  const float* w_in = (const float*)d_in[1];
  float* out = (float*)d_out;
  double* ws = (double*)d_ws;

  kInitWS<<<128, 256, 0, stream>>>(ws);
  sink_main<<<NBLK, 256, 0, stream>>>(feat, w_in, out, ws);
}